// Round 18
// baseline (55.230 us; speedup 1.0000x reference)
//
#include <hip/hip_runtime.h>
#include <math.h>

#define N_BINS 229
#define MODEL  128
#define OUTD   88
#define WSZ    30
#define WLEN   61
#define BB     4
#define TT     2048
#define CTANH  2.8853900817779268f   // 2*log2(e)

#define KPAD   256                   // padded K (229 -> 256 = 8 x 32)
#define NPAD   384                   // padded N (H 128 | E 128 | S1 88 | pad)
#define ROWS_F 8
#define FHALO  71
#define EPADU  68

typedef __attribute__((ext_vector_type(8))) short  short8v;  // 8 bf16 (4 VGPR)
typedef __attribute__((ext_vector_type(4))) float  f32x4;

__device__ __forceinline__ unsigned short bf16_rne(float x) {
    unsigned int u = __float_as_uint(x);
    return (unsigned short)((u + 0x7FFFu + ((u >> 16) & 1u)) >> 16);
}
__device__ __forceinline__ float sigmoidf_(float x) {
    return __builtin_amdgcn_rcpf(1.0f + __expf(-x));
}

// ---- Prep: Wt[n][k] = bf16 of (W_h*C | W_e*C | W1)^T, zero-padded ----
__global__ __launch_bounds__(256) void k_prep_w(
        const float* __restrict__ W_h, const float* __restrict__ W_e,
        const float* __restrict__ W1, unsigned short* __restrict__ Wt) {
    const int n = blockIdx.x;        // 0..383
    const int k = threadIdx.x;       // 0..255
    float v = 0.0f;
    if (k < N_BINS) {
        if (n < 128)      v = W_h[k * MODEL + n] * CTANH;
        else if (n < 256) v = W_e[k * MODEL + (n - 128)] * CTANH;
        else if (n < 344) v = W1[k * OUTD + (n - 256)];
    }
    Wt[n * KPAD + k] = bf16_rne(v);
}

// ---- Pass 1 (MFMA GEMM, LDS-free / barrier-free) ----
// [8192 x 229] @ [229 x 344] -> H (f32), Ebf (bf16 pairs), S1b (bf16 pairs).
// Per block: BM=16, 8 waves x 3 n-tiles. All fragments register-resident:
// B via aligned dwordx4 from L2-resident Wt; A via guarded scalar loads +
// in-register fp32->bf16 hi/lo split (2 MFMAs/tile kills A-side rounding).
// D layout (verified r17): D[(lane>>4)*4 + r][lane&15].
__global__ __launch_bounds__(512, 4) void k_he_mfma(
        const float* __restrict__ spec,
        const unsigned short* __restrict__ Wt,
        const float* __restrict__ b_attn,
        float* __restrict__ H,
        unsigned int* __restrict__ Ebf,
        unsigned int* __restrict__ S1b) {
    const int tid   = threadIdx.x;
    const int lane  = tid & 63;
    const int wv    = tid >> 6;          // 0..7
    const int gm0   = blockIdx.x * 16;
    const int mfrag = lane & 15;
    const int kg    = lane >> 4;         // 0..3
    const int n0    = wv * 48;

    f32x4 acc0 = {0,0,0,0}, acc1 = {0,0,0,0}, acc2 = {0,0,0,0};

    const float* __restrict__ sp = spec + (size_t)(gm0 + mfrag) * N_BINS;
    const unsigned short* __restrict__ B0 = Wt + (size_t)(n0      + mfrag) * KPAD;
    const unsigned short* __restrict__ B1 = Wt + (size_t)(n0 + 16 + mfrag) * KPAD;
    const unsigned short* __restrict__ B2 = Wt + (size_t)(n0 + 32 + mfrag) * KPAD;

    for (int kb = 0; kb < 8; ++kb) {
        const int k0 = kb * 32 + kg * 8;
        float v[8];
#pragma unroll
        for (int j = 0; j < 8; ++j)
            v[j] = (k0 + j < N_BINS) ? sp[k0 + j] : 0.0f;
        short8v ah, al;
#pragma unroll
        for (int j = 0; j < 8; ++j) {
            const unsigned short h = bf16_rne(v[j]);
            const float rr = v[j] - __uint_as_float((unsigned int)h << 16);
            ah[j] = (short)h;
            al[j] = (short)bf16_rne(rr);
        }
        const short8v b0 = *(const short8v*)(B0 + k0);   // 16B aligned
        const short8v b1 = *(const short8v*)(B1 + k0);
        const short8v b2 = *(const short8v*)(B2 + k0);
        acc0 = __builtin_amdgcn_mfma_f32_16x16x32_bf16(ah, b0, acc0, 0, 0, 0);
        acc0 = __builtin_amdgcn_mfma_f32_16x16x32_bf16(al, b0, acc0, 0, 0, 0);
        acc1 = __builtin_amdgcn_mfma_f32_16x16x32_bf16(ah, b1, acc1, 0, 0, 0);
        acc1 = __builtin_amdgcn_mfma_f32_16x16x32_bf16(al, b1, acc1, 0, 0, 0);
        acc2 = __builtin_amdgcn_mfma_f32_16x16x32_bf16(ah, b2, acc2, 0, 0, 0);
        acc2 = __builtin_amdgcn_mfma_f32_16x16x32_bf16(al, b2, acc2, 0, 0, 0);
    }

    // ---- epilogue: route tiles to H / Ebf / S1b (region uniform per tile) ----
#pragma unroll
    for (int t = 0; t < 3; ++t) {
        const f32x4 acc = (t == 0) ? acc0 : (t == 1) ? acc1 : acc2;
        const int gn = n0 + t * 16 + mfrag;
        if (gn < 128) {
            const float bc = b_attn[gn] * CTANH;
#pragma unroll
            for (int r = 0; r < 4; ++r) {
                const int gm = gm0 + (kg << 2) + r;
                H[(size_t)gm * MODEL + gn] = acc[r] + bc;
            }
        } else if (gn < 256) {
            const int ne = gn - 128;
#pragma unroll
            for (int r = 0; r < 4; ++r) {
                const float own = acc[r];
                const float pv  = __shfl_xor(own, 1, 64);
                if ((ne & 1) == 0) {
                    const int gm = gm0 + (kg << 2) + r;
                    Ebf[(size_t)gm * 64 + (ne >> 1)] =
                        (unsigned int)bf16_rne(own) |
                        ((unsigned int)bf16_rne(pv) << 16);
                }
            }
        } else if (gn < 344) {
            const int ns = gn - 256;
#pragma unroll
            for (int r = 0; r < 4; ++r) {
                const float own = acc[r];
                const float pv  = __shfl_xor(own, 1, 64);
                if ((ns & 1) == 0) {
                    const int gm = gm0 + (kg << 2) + r;
                    S1b[(size_t)gm * 44 + (ns >> 1)] =
                        (unsigned int)bf16_rne(own) |
                        ((unsigned int)bf16_rne(pv) << 16);
                }
            }
        }
    }
}

// ---- Pass 2 (fused): scores + softmax + 88-dim pooling + sigmoid ----
// 512 threads = 8 waves = 8 rows, 1024 blocks. LDS union: bf16-E halo during
// scores, bf16-S1 halo during pooling (both halved vs fp32).
__global__ __launch_bounds__(512, 4) void k_fused(
        const float* __restrict__ H,
        const unsigned int* __restrict__ Ebf,
        const float* __restrict__ v_w,
        const unsigned int* __restrict__ S1b,
        const float* __restrict__ b1,
        float* __restrict__ pred,
        float* __restrict__ a_out) {
    const int nb   = blockIdx.x;
    const int tid  = threadIdx.x;
    const int wv   = tid >> 6;              // 0..7 = local row
    const int lane = tid & 63;
    const int r0   = nb * ROWS_F;
    const int b    = r0 >> 11;              // T = 2048
    const int t0   = r0 & (TT - 1);
    const int r    = r0 + wv;
    const int t    = t0 + wv;

    __shared__ __align__(16) unsigned char ubuf[FHALO * EPADU * 4];  // 19312 B
    unsigned int* Ebs = (unsigned int*)ubuf;        // [FHALO][EPADU]
    unsigned int* S1u = (unsigned int*)ubuf;        // [FHALO][44]
    __shared__ float4 Hs4[ROWS_F * 32];             //  4096 B
    __shared__ float4 Vs4[32];                      //   512 B
    __shared__ float  scA[ROWS_F][64];              //  2048 B
    __shared__ float  cf[ROWS_F][64];               //  2048 B (total ~28 KB)

    // ---- stage bf16 E halo (zero outside [0,TT) == reference zero-pad) ----
    const uint4* __restrict__ Eb16 = (const uint4*)Ebf + (size_t)b * TT * 16;
    for (int i = tid; i < FHALO * 16; i += 512) {
        const int row = i >> 4, c = i & 15;
        const int s   = t0 - WSZ + row;
        uint4 v = make_uint4(0u, 0u, 0u, 0u);
        if (s >= 0 && s < TT) v = Eb16[(size_t)s * 16 + c];
        *(uint4*)&Ebs[row * EPADU + (c << 2)] = v;
    }
    if (tid < ROWS_F * 32)
        Hs4[tid] = ((const float4*)H)[(size_t)r0 * 32 + tid];
    else if (tid < ROWS_F * 32 + 32)
        Vs4[tid - ROWS_F * 32] = ((const float4*)v_w)[tid - ROWS_F * 32];
    __syncthreads();

    const int g  = lane & 3;
    const int w0 = lane >> 2;

    // ---- Sum(v_w), hoisted ----
    float vs = 0.f;
#pragma unroll
    for (int q = 0; q < 8; ++q) {
        const float4 vq = Vs4[(q << 2) + g];
        vs += (vq.x + vq.y) + (vq.z + vq.w);
    }
    vs += __shfl_xor(vs, 1, 64);
    vs += __shfl_xor(vs, 2, 64);

    // ---- scores for row wv ----
    int ro[4];
#pragma unroll
    for (int it = 0; it < 4; ++it)
        ro[it] = (wv + w0 + it * 16) * EPADU;       // hi in [0,70]

    const float4* __restrict__ HsR = &Hs4[wv * 32];

    float pp[4] = {0.f, 0.f, 0.f, 0.f};
#pragma unroll
    for (int q = 0; q < 8; ++q) {
        const int    cq = (q << 2) + g;
        const float4 hq = HsR[cq];          // pre-scaled by CTANH
        const float4 vq = Vs4[cq];
        const float nx = -2.f * vq.x, ny = -2.f * vq.y,
                    nz = -2.f * vq.z, nw = -2.f * vq.w;
#pragma unroll
        for (int it = 0; it < 4; ++it) {
            const uint2 e2 = *(const uint2*)&Ebs[ro[it] + (cq << 1)];
            const float f0 = __uint_as_float(e2.x << 16);
            const float f1 = __uint_as_float(e2.x & 0xFFFF0000u);
            const float f2 = __uint_as_float(e2.y << 16);
            const float f3 = __uint_as_float(e2.y & 0xFFFF0000u);
            float u;
            u = __builtin_amdgcn_rcpf(__builtin_amdgcn_exp2f(f0 + hq.x) + 1.f);
            pp[it] = fmaf(nx, u, pp[it]);
            u = __builtin_amdgcn_rcpf(__builtin_amdgcn_exp2f(f1 + hq.y) + 1.f);
            pp[it] = fmaf(ny, u, pp[it]);
            u = __builtin_amdgcn_rcpf(__builtin_amdgcn_exp2f(f2 + hq.z) + 1.f);
            pp[it] = fmaf(nz, u, pp[it]);
            u = __builtin_amdgcn_rcpf(__builtin_amdgcn_exp2f(f3 + hq.w) + 1.f);
            pp[it] = fmaf(nw, u, pp[it]);
        }
    }
#pragma unroll
    for (int it = 0; it < 4; ++it) {
        float p = pp[it];
        p += __shfl_xor(p, 1, 64);
        p += __shfl_xor(p, 2, 64);
        const int w = w0 + it * 16;
        if (g == 0 && w < WLEN) scA[wv][w] = p + vs;
    }

    // ---- wave-local softmax (same wave wrote scA[wv]) ----
    {
        float x = (lane < WLEN) ? scA[wv][lane] : -INFINITY;
        float mx = x;
#pragma unroll
        for (int d = 32; d >= 1; d >>= 1) mx = fmaxf(mx, __shfl_xor(mx, d, 64));
        float e = (lane < WLEN) ? __expf(x - mx) : 0.0f;
        float sm = e;
#pragma unroll
        for (int d = 32; d >= 1; d >>= 1) sm += __shfl_xor(sm, d, 64);
        const float a = e * __builtin_amdgcn_rcpf(sm);
        if (lane < WLEN) a_out[(size_t)r * WLEN + lane] = a;
        const int sl = t + lane - WSZ;
        cf[wv][lane] = (lane < WLEN && sl >= 0 && sl < TT) ? a : 0.0f;
    }

    __syncthreads();                        // all waves done reading Ebs

    // ---- re-stage union with bf16 S1 halo (zero outside [0,TT)) ----
    const uint4* __restrict__ Sb4 = (const uint4*)S1b + (size_t)b * TT * 11;
    for (int i = tid; i < FHALO * 11; i += 512) {
        const int row = i / 11, c = i - row * 11;
        const int s   = t0 - WSZ + row;
        uint4 v = make_uint4(0u, 0u, 0u, 0u);
        if (s >= 0 && s < TT) v = Sb4[(size_t)s * 11 + c];
        *(uint4*)&S1u[row * 44 + (c << 2)] = v;
    }
    __syncthreads();

    // ---- pooling row wv: lane < 44 handles outputs (2*lane, 2*lane+1) ----
    if (lane < 44) {
        float a1 = 0.f, a2 = 0.f;
#pragma unroll 4
        for (int w = 0; w < 64; ++w) {
            const float at = cf[wv][w];                 // LDS broadcast
            const unsigned int pv = S1u[(wv + w) * 44 + lane];
            a1 = fmaf(at, __uint_as_float(pv << 16),         a1);
            a2 = fmaf(at, __uint_as_float(pv & 0xFFFF0000u), a2);
        }
        const int o = lane << 1;
        pred[(size_t)r * OUTD + o]     = sigmoidf_(a1 + b1[o]);
        pred[(size_t)r * OUTD + o + 1] = sigmoidf_(a2 + b1[o + 1]);
    }
}

extern "C" void kernel_launch(void* const* d_in, const int* in_sizes, int n_in,
                              void* d_out, int out_size, void* d_ws, size_t ws_size,
                              hipStream_t stream) {
    const float* spec   = (const float*)d_in[0];
    const float* W_h    = (const float*)d_in[1];
    const float* W_e    = (const float*)d_in[2];
    const float* b_attn = (const float*)d_in[3];
    const float* v_w    = (const float*)d_in[4];
    const float* W1     = (const float*)d_in[5];
    const float* b1     = (const float*)d_in[6];

    const int n_rows = BB * TT;                       // 8192
    char* ws = (char*)d_ws;
    float*          H   = (float*)ws;                               // 4 MB
    unsigned int*   Ebf = (unsigned int*)(ws + ((size_t)4 << 20));  // 2 MB
    unsigned int*   S1b = (unsigned int*)(ws + ((size_t)6 << 20));  // 1.44 MB
    unsigned short* Wt  = (unsigned short*)(ws + ((size_t)8 << 20)); // 192 KB

    float* pred  = (float*)d_out;                     // 8192*88
    float* a_out = pred + (size_t)n_rows * OUTD;      // 8192*61

    k_prep_w <<<NPAD,            256, 0, stream>>>(W_h, W_e, W1, Wt);
    k_he_mfma<<<n_rows / 16,     512, 0, stream>>>(spec, Wt, b_attn, H, Ebf, S1b);
    k_fused  <<<n_rows / ROWS_F, 512, 0, stream>>>(H, Ebf, v_w, S1b, b1,
                                                   pred, a_out);
}